// Round 7
// baseline (190.928 us; speedup 1.0000x reference)
//
#include <hip/hip_runtime.h>

typedef unsigned int uint32;
typedef unsigned short ushrt;
typedef __attribute__((ext_vector_type(4))) float f32x4;
typedef __attribute__((ext_vector_type(8))) _Float16 halfx8;
typedef __attribute__((ext_vector_type(4))) uint32 uint32x4;

#define N_NODES 10000
#define N_EDGES 320000

// scales
#define SC_W1      0.17677669529663687f   // 1/sqrt(32)
#define SC_MLP1    0.35355339059327373f   // 1/sqrt(8)
#define SC_MLP2    0.125f                 // 1/sqrt(64)
#define INV_SQRT3  0.5773502691896258f
#define COS_MIX    0.9238795325112867f    // cos(pi/8)
#define SIN_CONV   0.04783542904563623f   // sin(pi/8) / sqrt(64)

// ws layout
#define WS_FEATP 0        // [N][128] floats, planar: f0 | f1x | f1y | f1z
// int indices (on (int*)ws)
#define I_CNT    1280000  // [N+1]
#define I_OFF    1290016  // [N+1]  (mutated by scatter; node_conv uses off-cnt)
#define I_ORD    1300032  // [E]
#define I_ESRC   1620032  // [E] ushorts (160000 ints)
// uint indices (on (uint*)ws)
#define U_WF     1780032  // 28 frags x 64 lanes x 4 uints

__device__ __forceinline__ uint32 f2bf(float x) {
    uint32 u = __float_as_uint(x);
    return (u + 0x7fffu + ((u >> 16) & 1u)) >> 16;
}
__device__ __forceinline__ uint32 pack_bf2(float a, float b) {
    return f2bf(a) | (f2bf(b) << 16);
}
__device__ __forceinline__ uint32 packh2(float a, float b) {
    _Float16 ha = (_Float16)a, hb = (_Float16)b;
    return (uint32)__builtin_bit_cast(unsigned short, ha) |
           ((uint32)__builtin_bit_cast(unsigned short, hb) << 16);
}
__device__ __forceinline__ unsigned short h16(float x) {
    _Float16 h = (_Float16)x;
    return __builtin_bit_cast(unsigned short, h);
}
__device__ __forceinline__ float gelu_fast(float x) {
    float x2 = x * x;
    float z = x * __builtin_fmaf(0.03567740814f, x2, 0.7978845608f);
    float E = __builtin_amdgcn_exp2f(z * -2.885390082f);
    return x * __builtin_amdgcn_rcpf(1.0f + E);
}

// ================= K1: node_transform | csr_count | prep_frags ====
#define K1_NODE_BLOCKS 2500
#define K1_CNT_BLOCKS  1250
#define K1_PREP_BLOCKS 7
__global__ __launch_bounds__(256) void k1_fused(
        const float* __restrict__ x,
        const float* __restrict__ W1_0e, const float* __restrict__ W1_1o,
        const int* __restrict__ edge_dst, int* __restrict__ cnt,
        const float* __restrict__ Wm1, const float* __restrict__ Wm2,
        const float* __restrict__ Wp00, const float* __restrict__ Wp01,
        const float* __restrict__ Wp10, const float* __restrict__ Wp11,
        uint32* __restrict__ wf,
        float* __restrict__ featp, float* __restrict__ out) {
    int b = blockIdx.x;
    if (b < K1_NODE_BLOCKS) {
        __shared__ float xrow[4][128];
        int wv = threadIdx.x >> 6, lane = threadIdx.x & 63;
        int node = b * 4 + wv;
        float2 v = *(const float2*)(x + (size_t)node * 128 + lane * 2);
        xrow[wv][lane * 2]     = v.x;
        xrow[wv][lane * 2 + 1] = v.y;
        __syncthreads();
        const float* sx = xrow[wv];
        int w = lane;
        float f0 = 0.f, f1x = 0.f, f1y = 0.f, f1z = 0.f;
#pragma unroll
        for (int u = 0; u < 32; ++u) {
            float w0 = W1_0e[u * 64 + w];
            float w1 = W1_1o[u * 64 + w];
            f0  += sx[u] * w0;
            f1x += sx[32 + u * 3 + 0] * w1;
            f1y += sx[32 + u * 3 + 1] * w1;
            f1z += sx[32 + u * 3 + 2] * w1;
        }
        f0 *= SC_W1; f1x *= SC_W1; f1y *= SC_W1; f1z *= SC_W1;
        if (w < 32) {
            featp[node * 128 + w]      = f0;
            featp[node * 128 + 32 + w] = f1x;
            featp[node * 128 + 64 + w] = f1y;
            featp[node * 128 + 96 + w] = f1z;
        } else {
            int ww = w - 32;
            out[node * 128 + ww] = COS_MIX * f0;
            out[node * 128 + 32 + ww * 3 + 0] = COS_MIX * f1x;
            out[node * 128 + 32 + ww * 3 + 1] = COS_MIX * f1y;
            out[node * 128 + 32 + ww * 3 + 2] = COS_MIX * f1z;
        }
    } else if (b < K1_NODE_BLOCKS + K1_CNT_BLOCKS) {
        int e = (b - K1_NODE_BLOCKS) * 256 + threadIdx.x;
        atomicAdd(&cnt[edge_dst[e]], 1);
    } else {
        int gid = (b - K1_NODE_BLOCKS - K1_CNT_BLOCKS) * 256 + threadIdx.x;
        int f = gid >> 6, lane = gid & 63;
        int kq = (lane >> 4) * 8;
        int c15 = lane & 15;
        float vals[8];
        if (f < 4) {
            int c = 16 * f + c15;
#pragma unroll
            for (int j = 0; j < 8; ++j) { int k = kq + j; vals[j] = (k < 8) ? Wm1[k * 64 + c] : 0.f; }
        } else if (f < 12) {
            int idx = f - 4, nt = idx >> 1, ks = idx & 1;
            int c = 16 * nt + c15;
#pragma unroll
            for (int j = 0; j < 8; ++j) { int k = 32 * ks + kq + j; vals[j] = Wm2[k * 64 + c]; }
        } else {
            int idx = f - 12, nt = idx >> 1, ks = idx & 1;
            int c = 16 * nt + c15;
            int u = c & 31, m = c >> 5;
            const float* W = (m == 0) ? Wp00 : (m == 1) ? Wp01 : (m == 2) ? Wp10 : Wp11;
            float sc = (m == 3) ? 0.125f * INV_SQRT3 : 0.125f;
#pragma unroll
            for (int j = 0; j < 8; ++j) { int k = 32 * ks + kq + j; vals[j] = W[k * 32 + u] * sc; }
        }
        uint32* o = wf + f * 256 + lane * 4;
#pragma unroll
        for (int w = 0; w < 4; ++w) o[w] = packh2(vals[2 * w], vals[2 * w + 1]);
    }
}

// ================= K2: csr_scan (single block) =================
__global__ __launch_bounds__(256) void csr_scan(const int* __restrict__ cnt,
                                                int* __restrict__ off) {
    __shared__ int partial[256];
    int t = threadIdx.x;
    const int CHUNK = 40;
    int base = t * CHUNK;
    int s = 0;
#pragma unroll
    for (int j = 0; j < CHUNK; ++j) {
        int idx = base + j;
        s += (idx < N_NODES) ? cnt[idx] : 0;
    }
    partial[t] = s;
    __syncthreads();
    for (int o = 1; o < 256; o <<= 1) {
        int v = partial[t];
        int add = (t >= o) ? partial[t - o] : 0;
        __syncthreads();
        partial[t] = v + add;
        __syncthreads();
    }
    int run = (t > 0) ? partial[t - 1] : 0;
    for (int j = 0; j < CHUNK; ++j) {
        int idx = base + j;
        if (idx < N_NODES) {
            off[idx] = run;
            run += cnt[idx];
        }
    }
    if (t == 255) off[N_NODES] = run;
}

// ================= K3: csr_scatter (mutates off; node_conv uses off-cnt) =====
__global__ __launch_bounds__(256) void csr_scatter(const int* __restrict__ src,
                                                   const int* __restrict__ dst,
                                                   int* __restrict__ off,
                                                   int* __restrict__ ord,
                                                   ushrt* __restrict__ esrc) {
    int e = blockIdx.x * 256 + threadIdx.x;   // grid 1250 exact
    int pos = atomicAdd(&off[dst[e]], 1);
    ord[pos] = e;
    esrc[pos] = (ushrt)src[e];
}

// ================= K4: node_conv — fused per-node MFMA MLP + gather ==========
// Wave per node. For each group of <=16 of the node's CSR edges:
//   MLP (28 MFMA, weights: wb1/wb2 in regs, wbp in block LDS)
//   -> pack bf16 coefficient pairs into wave-private LDS (4KB)
//   -> consume immediately (feat gathers L2/L3-hot), 4-deep pipelined.
// Group g+1's gathered loads are issued under group g's compute.
__global__ __launch_bounds__(256) void node_conv(
        const int* __restrict__ off, const int* __restrict__ cnt,
        const int* __restrict__ ord, const ushrt* __restrict__ esrc,
        const float* __restrict__ edge_scalar, const float* __restrict__ edge_attr,
        const uint32* __restrict__ wf, const float* __restrict__ featp,
        const float* __restrict__ W2_0e, const float* __restrict__ W2_1o,
        float* __restrict__ out) {
    __shared__ uint32x4 wbp_lds[16 * 64];      // 16KB: projection frags 12..27
    __shared__ unsigned short sh[4][1024];     // 8KB: MLP staging (XOR-swizzled)
    __shared__ uint32 wlds[4][16 * 64];        // 16KB: packed w per wave
    __shared__ float4 ea_lds[4][16];           // 1KB
    __shared__ int    src_lds[4][16];          // 256B
    __shared__ float  red[4][256];             // 4KB

    // cooperative copy of wbp fragments into LDS
    {
        const uint32x4* s = (const uint32x4*)(wf + 12 * 256);
        for (int i = threadIdx.x; i < 16 * 64; i += 256) wbp_lds[i] = s[i];
    }

    int lane = threadIdx.x & 63;
    int wvq = threadIdx.x >> 6;
    int node = blockIdx.x * 4 + wvq;
    int kq = (lane >> 4) * 8;
    int r15 = lane & 15;
    int u = lane & 31;
    int half = lane >> 5;

    // wb1/wb2 fragments in registers (48 VGPR)
    const uint32x4* wfp = (const uint32x4*)wf;
    halfx8 wb1[4], wb2[4][2];
#pragma unroll
    for (int nt = 0; nt < 4; ++nt)
        wb1[nt] = __builtin_bit_cast(halfx8, wfp[nt * 64 + lane]);
#pragma unroll
    for (int nt = 0; nt < 4; ++nt)
#pragma unroll
        for (int ks = 0; ks < 2; ++ks)
            wb2[nt][ks] = __builtin_bit_cast(halfx8, wfp[(4 + nt * 2 + ks) * 64 + lane]);

    __syncthreads();   // wbp_lds ready

    int end = __builtin_amdgcn_readfirstlane(off[node]);   // off mutated = end
    int beg = end - __builtin_amdgcn_readfirstlane(cnt[node]);
    int ng = (end - beg + 15) >> 4;

    float a0acc = 0.f, a1x = 0.f, a1y = 0.f, a1z = 0.f;

    const f32x4 z4 = {0.f, 0.f, 0.f, 0.f};
    unsigned short* shw = sh[wvq];
    uint32* wld = wlds[wvq];
    int offA = u + half * 32, offB = 64 + u, offC = 96 + u;

    // group-gather registers (lane<16 meaningful)
    float4 es0n = {0,0,0,0}, es1n = {0,0,0,0}, ean = {0,0,0,0};
    int srcn = 0;
    auto LOADG = [&](int g) {
        int pp = beg + g * 16 + lane;
        bool v = (lane < 16) && (pp < end);
        int idx = v ? pp : beg;
        int e = ord[idx];
        const float* esp = edge_scalar + (size_t)e * 8;
        float4 p0 = *(const float4*)esp;
        float4 p1 = *(const float4*)(esp + 4);
        float4 av = *(const float4*)(edge_attr + (size_t)e * 4);
        float4 zf = {0,0,0,0};
        es0n = v ? p0 : zf;
        es1n = v ? p1 : zf;
        ean  = v ? av : zf;
        srcn = v ? (int)esrc[idx] : 0;
    };

    if (ng > 0) LOADG(0);

    for (int g = 0; g < ng; ++g) {
        int rem = end - (beg + g * 16);
        if (rem > 16) rem = 16;

        float4 es0c = es0n, es1c = es1n, eac = ean;
        int srcc = srcn;
        if (lane < 16) {
            ea_lds[wvq][lane] = eac;
            src_lds[wvq][lane] = srcc;
        }

        halfx8 a0 = (halfx8)0;
        if (lane < 16) {
            a0[0] = (_Float16)es0c.x; a0[1] = (_Float16)es0c.y;
            a0[2] = (_Float16)es0c.z; a0[3] = (_Float16)es0c.w;
            a0[4] = (_Float16)es1c.x; a0[5] = (_Float16)es1c.y;
            a0[6] = (_Float16)es1c.z; a0[7] = (_Float16)es1c.w;
        }

        // h1 GEMM
        f32x4 acc1[4];
#pragma unroll
        for (int nt = 0; nt < 4; ++nt)
            acc1[nt] = __builtin_amdgcn_mfma_f32_16x16x32_f16(a0, wb1[nt], z4, 0, 0, 0);

        // prefetch next group's gathered data under the compute chain
        if (g + 1 < ng) LOADG(g + 1);

#pragma unroll
        for (int nt = 0; nt < 4; ++nt)
#pragma unroll
            for (int i = 0; i < 4; ++i) {
                float gv = gelu_fast(acc1[nt][i] * SC_MLP1);
                int rr = (lane >> 4) * 4 + i;
                int ix = rr * 64 + 16 * nt + r15;
                shw[ix ^ ((rr & 7) << 3)] = h16(gv);
            }
        halfx8 a1[2];
#pragma unroll
        for (int ks = 0; ks < 2; ++ks) {
            int ix = r15 * 64 + 32 * ks + kq;
            a1[ks] = __builtin_bit_cast(halfx8,
                       *(const uint32x4*)&shw[ix ^ ((r15 & 7) << 3)]);
        }

        // h2 GEMM
        f32x4 acc2[4];
#pragma unroll
        for (int nt = 0; nt < 4; ++nt) {
            acc2[nt] = __builtin_amdgcn_mfma_f32_16x16x32_f16(a1[0], wb2[nt][0], z4, 0, 0, 0);
            acc2[nt] = __builtin_amdgcn_mfma_f32_16x16x32_f16(a1[1], wb2[nt][1], acc2[nt], 0, 0, 0);
        }
#pragma unroll
        for (int nt = 0; nt < 4; ++nt)
#pragma unroll
            for (int i = 0; i < 4; ++i) {
                float gv = gelu_fast(acc2[nt][i] * SC_MLP2);
                int rr = (lane >> 4) * 4 + i;
                int ix = rr * 64 + 16 * nt + r15;
                shw[ix ^ ((rr & 7) << 3)] = h16(gv);
            }
        halfx8 a2[2];
#pragma unroll
        for (int ks = 0; ks < 2; ++ks) {
            int ix = r15 * 64 + 32 * ks + kq;
            a2[ks] = __builtin_bit_cast(halfx8,
                       *(const uint32x4*)&shw[ix ^ ((r15 & 7) << 3)]);
        }

        // projection GEMM, wbp fragments from LDS
        f32x4 accp[8];
#pragma unroll
        for (int nt = 0; nt < 8; ++nt) {
            halfx8 b0 = __builtin_bit_cast(halfx8, wbp_lds[(nt * 2 + 0) * 64 + lane]);
            halfx8 b1 = __builtin_bit_cast(halfx8, wbp_lds[(nt * 2 + 1) * 64 + lane]);
            accp[nt] = __builtin_amdgcn_mfma_f32_16x16x32_f16(a2[0], b0, z4, 0, 0, 0);
            accp[nt] = __builtin_amdgcn_mfma_f32_16x16x32_f16(a2[1], b1, accp[nt], 0, 0, 0);
        }

        // fold ea.x, pack to wave-private LDS
#pragma unroll
        for (int i = 0; i < 4; ++i) {
            int rr = (lane >> 4) * 4 + i;
            float eax = ea_lds[wvq][rr].x;
            uint32* wrow = wld + rr * 64 + r15;
            wrow[0]  = pack_bf2(accp[0][i] * eax, accp[2][i]);
            wrow[16] = pack_bf2(accp[1][i] * eax, accp[3][i]);
            wrow[32] = pack_bf2(accp[4][i] * eax, accp[6][i]);
            wrow[48] = pack_bf2(accp[5][i] * eax, accp[7][i]);
        }

        // consume rem edges (4-deep pipelined)
        for (int j0 = 0; j0 < rem; j0 += 4) {
            uint32 wl_[4];
            float fa_[4], fb_[4], fc_[4], ey_[4], ez_[4], ew_[4];
#pragma unroll
            for (int t = 0; t < 4; ++t) {
                int j = j0 + t;
                int jc = (j < rem) ? j : rem - 1;
                float4 ea = ea_lds[wvq][jc];
                int s = src_lds[wvq][jc];
                uint32 wl = wld[jc * 64 + lane];
                wl_[t] = (j < rem) ? wl : 0u;
                const float* fp = featp + (size_t)s * 128;
                fa_[t] = fp[offA];
                fb_[t] = fp[offB];
                fc_[t] = fp[offC];
                ey_[t] = ea.y; ez_[t] = ea.z; ew_[t] = ea.w;
            }
#pragma unroll
            for (int t = 0; t < 4; ++t) {
                float wa = __uint_as_float(wl_[t] << 16);
                float wb = __uint_as_float(wl_[t] & 0xffff0000u);
                float va = half ? ey_[t] : 1.0f;
                float vb = half ? ez_[t] : 0.0f;
                float vc = half ? ew_[t] : 0.0f;
                float dot = fa_[t] * va + fb_[t] * vb + fc_[t] * vc;
                float w0s = half ? wb : wa;
                a0acc += w0s * dot;
                float m  = half ? wa : wb * fa_[t];
                float vx = half ? fa_[t] : ey_[t];
                float vy = half ? fb_[t] : ez_[t];
                float vz = half ? fc_[t] : ew_[t];
                a1x += m * vx; a1y += m * vy; a1z += m * vz;
            }
        }
    }

    // block reduction + W2 epilogue
    float* r = red[wvq];
    int c = (half << 5) + u;
    r[c] = a0acc;
    int b = 64 + c * 3;
    r[b] = a1x; r[b + 1] = a1y; r[b + 2] = a1z;
    __syncthreads();

    if (half == 0) {
        float acc = 0.f;
#pragma unroll 8
        for (int w = 0; w < 64; ++w) acc += r[w] * W2_0e[w * 32 + u];
        int o = node * 128 + u;
        out[o] = out[o] + SIN_CONV * acc;          // prefilled with COS_MIX*self
    } else {
        float c0 = 0.f, c1 = 0.f, c2 = 0.f;
#pragma unroll 8
        for (int w = 0; w < 64; ++w) {
            float bw = W2_1o[w * 32 + u];
            c0 += r[64 + w * 3 + 0] * bw;
            c1 += r[64 + w * 3 + 1] * bw;
            c2 += r[64 + w * 3 + 2] * bw;
        }
        int o = node * 128 + 32 + u * 3;
        out[o + 0] = out[o + 0] + SIN_CONV * c0;
        out[o + 1] = out[o + 1] + SIN_CONV * c1;
        out[o + 2] = out[o + 2] + SIN_CONV * c2;
    }
}

extern "C" void kernel_launch(void* const* d_in, const int* in_sizes, int n_in,
                              void* d_out, int out_size, void* d_ws, size_t ws_size,
                              hipStream_t stream) {
    const float* node_input  = (const float*)d_in[0];
    const float* edge_attr   = (const float*)d_in[1];
    const float* edge_scalar = (const float*)d_in[2];
    const float* W1_0e       = (const float*)d_in[3];
    const float* W1_1o       = (const float*)d_in[4];
    const float* W_mlp1      = (const float*)d_in[5];
    const float* W_mlp2      = (const float*)d_in[6];
    const float* Wp00        = (const float*)d_in[7];
    const float* Wp01        = (const float*)d_in[8];
    const float* Wp10        = (const float*)d_in[9];
    const float* Wp11        = (const float*)d_in[10];
    const float* W2_0e       = (const float*)d_in[11];
    const float* W2_1o       = (const float*)d_in[12];
    const int*   edge_src    = (const int*)d_in[13];
    const int*   edge_dst    = (const int*)d_in[14];
    float* ws   = (float*)d_ws;
    int*   wsI  = (int*)d_ws;
    uint32* wsU = (uint32*)d_ws;
    ushrt* esrcp = (ushrt*)(wsI + I_ESRC);
    float* outp = (float*)d_out;

    hipMemsetAsync(wsI + I_CNT, 0, (N_NODES + 1) * sizeof(int), stream);

    k1_fused<<<K1_NODE_BLOCKS + K1_CNT_BLOCKS + K1_PREP_BLOCKS, 256, 0, stream>>>(
        node_input, W1_0e, W1_1o, edge_dst, wsI + I_CNT,
        W_mlp1, W_mlp2, Wp00, Wp01, Wp10, Wp11, wsU + U_WF, ws + WS_FEATP, outp);
    csr_scan<<<1, 256, 0, stream>>>(wsI + I_CNT, wsI + I_OFF);
    csr_scatter<<<1250, 256, 0, stream>>>(edge_src, edge_dst, wsI + I_OFF,
                                          wsI + I_ORD, esrcp);
    node_conv<<<N_NODES / 4, 256, 0, stream>>>(wsI + I_OFF, wsI + I_CNT, wsI + I_ORD,
                                               esrcp, edge_scalar, edge_attr,
                                               wsU + U_WF, ws + WS_FEATP,
                                               W2_0e, W2_1o, outp);
}

// Round 8
// 126.286 us; speedup vs baseline: 1.5119x; 1.5119x over previous
//
#include <hip/hip_runtime.h>

typedef unsigned int uint32;
typedef __attribute__((ext_vector_type(4))) float f32x4;
typedef __attribute__((ext_vector_type(8))) _Float16 halfx8;
typedef __attribute__((ext_vector_type(4))) uint32 uint32x4;

#define N_NODES 10000
#define N_EDGES 320000

// scales
#define SC_W1      0.17677669529663687f   // 1/sqrt(32)
#define SC_MLP1    0.35355339059327373f   // 1/sqrt(8)
#define SC_MLP2    0.125f                 // 1/sqrt(64)
#define INV_SQRT3  0.5773502691896258f
#define COS_MIX    0.9238795325112867f    // cos(pi/8)
#define SIN_CONV   0.04783542904563623f   // sin(pi/8) / sqrt(64)

// ws layout
#define WS_FEATP 0        // [N][128] floats, planar: f0 | f1x | f1y | f1z
// int indices (on (int*)ws)
#define I_CNT    1280000  // [N+1]
#define I_OFF    1290016  // [N+1]  (mutated by mlp_scatter; gather uses off-cnt)
#define U_REC    1300032  // [E] uint4: {ea.y, ea.z, ea.w bits, src}
#define U_WF     2580032  // 28 frags x 64 lanes x 4 uints
#define U_WBUF   2587200  // [E][64] packed bf16 pairs, CSR-position order

__device__ __forceinline__ uint32 f2bf(float x) {
    uint32 u = __float_as_uint(x);
    return (u + 0x7fffu + ((u >> 16) & 1u)) >> 16;
}
__device__ __forceinline__ uint32 pack_bf2(float a, float b) {
    return f2bf(a) | (f2bf(b) << 16);
}
__device__ __forceinline__ uint32 packh2(float a, float b) {
    _Float16 ha = (_Float16)a, hb = (_Float16)b;
    return (uint32)__builtin_bit_cast(unsigned short, ha) |
           ((uint32)__builtin_bit_cast(unsigned short, hb) << 16);
}
__device__ __forceinline__ unsigned short h16(float x) {
    _Float16 h = (_Float16)x;
    return __builtin_bit_cast(unsigned short, h);
}
__device__ __forceinline__ float gelu_fast(float x) {
    float x2 = x * x;
    float z = x * __builtin_fmaf(0.03567740814f, x2, 0.7978845608f);
    float E = __builtin_amdgcn_exp2f(z * -2.885390082f);
    return x * __builtin_amdgcn_rcpf(1.0f + E);
}

// ================= K1: node_transform | csr_count | prep_frags ====
#define K1_NODE_BLOCKS 2500
#define K1_CNT_BLOCKS  1250
#define K1_PREP_BLOCKS 7
__global__ __launch_bounds__(256) void k1_fused(
        const float* __restrict__ x,
        const float* __restrict__ W1_0e, const float* __restrict__ W1_1o,
        const int* __restrict__ edge_dst, int* __restrict__ cnt,
        const float* __restrict__ Wm1, const float* __restrict__ Wm2,
        const float* __restrict__ Wp00, const float* __restrict__ Wp01,
        const float* __restrict__ Wp10, const float* __restrict__ Wp11,
        uint32* __restrict__ wf,
        float* __restrict__ featp, float* __restrict__ out) {
    int b = blockIdx.x;
    if (b < K1_NODE_BLOCKS) {
        __shared__ float xrow[4][128];
        int wv = threadIdx.x >> 6, lane = threadIdx.x & 63;
        int node = b * 4 + wv;
        float2 v = *(const float2*)(x + (size_t)node * 128 + lane * 2);
        xrow[wv][lane * 2]     = v.x;
        xrow[wv][lane * 2 + 1] = v.y;
        __syncthreads();
        const float* sx = xrow[wv];
        int w = lane;
        float f0 = 0.f, f1x = 0.f, f1y = 0.f, f1z = 0.f;
#pragma unroll
        for (int u = 0; u < 32; ++u) {
            float w0 = W1_0e[u * 64 + w];
            float w1 = W1_1o[u * 64 + w];
            f0  += sx[u] * w0;
            f1x += sx[32 + u * 3 + 0] * w1;
            f1y += sx[32 + u * 3 + 1] * w1;
            f1z += sx[32 + u * 3 + 2] * w1;
        }
        f0 *= SC_W1; f1x *= SC_W1; f1y *= SC_W1; f1z *= SC_W1;
        if (w < 32) {
            featp[node * 128 + w]      = f0;
            featp[node * 128 + 32 + w] = f1x;
            featp[node * 128 + 64 + w] = f1y;
            featp[node * 128 + 96 + w] = f1z;
        } else {
            int ww = w - 32;
            out[node * 128 + ww] = COS_MIX * f0;
            out[node * 128 + 32 + ww * 3 + 0] = COS_MIX * f1x;
            out[node * 128 + 32 + ww * 3 + 1] = COS_MIX * f1y;
            out[node * 128 + 32 + ww * 3 + 2] = COS_MIX * f1z;
        }
    } else if (b < K1_NODE_BLOCKS + K1_CNT_BLOCKS) {
        int e = (b - K1_NODE_BLOCKS) * 256 + threadIdx.x;
        atomicAdd(&cnt[edge_dst[e]], 1);
    } else {
        int gid = (b - K1_NODE_BLOCKS - K1_CNT_BLOCKS) * 256 + threadIdx.x;
        int f = gid >> 6, lane = gid & 63;
        int kq = (lane >> 4) * 8;
        int c15 = lane & 15;
        float vals[8];
        if (f < 4) {
            int c = 16 * f + c15;
#pragma unroll
            for (int j = 0; j < 8; ++j) { int k = kq + j; vals[j] = (k < 8) ? Wm1[k * 64 + c] : 0.f; }
        } else if (f < 12) {
            int idx = f - 4, nt = idx >> 1, ks = idx & 1;
            int c = 16 * nt + c15;
#pragma unroll
            for (int j = 0; j < 8; ++j) { int k = 32 * ks + kq + j; vals[j] = Wm2[k * 64 + c]; }
        } else {
            int idx = f - 12, nt = idx >> 1, ks = idx & 1;
            int c = 16 * nt + c15;
            int u = c & 31, m = c >> 5;
            const float* W = (m == 0) ? Wp00 : (m == 1) ? Wp01 : (m == 2) ? Wp10 : Wp11;
            float sc = (m == 3) ? 0.125f * INV_SQRT3 : 0.125f;
#pragma unroll
            for (int j = 0; j < 8; ++j) { int k = 32 * ks + kq + j; vals[j] = W[k * 32 + u] * sc; }
        }
        uint32* o = wf + f * 256 + lane * 4;
#pragma unroll
        for (int w = 0; w < 4; ++w) o[w] = packh2(vals[2 * w], vals[2 * w + 1]);
    }
}

// ================= K2: csr_scan (single block, 1024 threads) =================
__global__ __launch_bounds__(1024) void csr_scan(const int* __restrict__ cnt,
                                                 int* __restrict__ off) {
    __shared__ int partial[1024];
    int t = threadIdx.x;
    const int CHUNK = 10;                      // 1024*10 = 10240 >= 10000
    int base = t * CHUNK;
    int s = 0;
#pragma unroll
    for (int j = 0; j < CHUNK; ++j) {
        int idx = base + j;
        s += (idx < N_NODES) ? cnt[idx] : 0;
    }
    partial[t] = s;
    __syncthreads();
    for (int o = 1; o < 1024; o <<= 1) {
        int v = partial[t];
        int add = (t >= o) ? partial[t - o] : 0;
        __syncthreads();
        partial[t] = v + add;
        __syncthreads();
    }
    int run = (t > 0) ? partial[t - 1] : 0;
    for (int j = 0; j < CHUNK; ++j) {
        int idx = base + j;
        if (idx < N_NODES) {
            off[idx] = run;
            run += cnt[idx];
        }
    }
    if (t == 1023) off[N_NODES] = run;
}

// ================= K3: mlp_scatter — MFMA MLP in original order, ============
// scatter coefficient rows + records to CSR positions.
#define MLP_BLOCKS 1250
__global__ __launch_bounds__(256) void mlp_scatter(
        const float* __restrict__ edge_scalar, const float* __restrict__ edge_attr,
        const int* __restrict__ src_in, const int* __restrict__ dst_in,
        int* __restrict__ off,
        const uint32* __restrict__ wf,
        uint32* __restrict__ wbuf, uint4* __restrict__ rec) {
    __shared__ unsigned short sh[4][1024];   // per-wave 16x64 f16 tile, XOR-swizzled
    __shared__ float eaxs[4][16];
    __shared__ int   poss[4][16];
    int lane = threadIdx.x & 63;
    int wvq = threadIdx.x >> 6;
    int wave_id = blockIdx.x * 4 + wvq;
    int kq = (lane >> 4) * 8;
    int r15 = lane & 15;

    // preload all 28 weight fragments into registers (proven layout)
    const uint32x4* wfp = (const uint32x4*)wf;
    halfx8 wb1[4], wb2[4][2], wbp[8][2];
#pragma unroll
    for (int nt = 0; nt < 4; ++nt)
        wb1[nt] = __builtin_bit_cast(halfx8, wfp[nt * 64 + lane]);
#pragma unroll
    for (int nt = 0; nt < 4; ++nt)
#pragma unroll
        for (int ks = 0; ks < 2; ++ks)
            wb2[nt][ks] = __builtin_bit_cast(halfx8, wfp[(4 + nt * 2 + ks) * 64 + lane]);
#pragma unroll
    for (int nt = 0; nt < 8; ++nt)
#pragma unroll
        for (int ks = 0; ks < 2; ++ks)
            wbp[nt][ks] = __builtin_bit_cast(halfx8, wfp[(12 + nt * 2 + ks) * 64 + lane]);

    const f32x4 z4 = {0.f, 0.f, 0.f, 0.f};
    unsigned short* shw = sh[wvq];

    for (int g = wave_id; g < N_EDGES / 16; g += MLP_BLOCKS * 4) {
        int e0 = g * 16;

        halfx8 a0 = (halfx8)0;
        if (lane < 16) {
            int e = e0 + lane;
            const float* esp = edge_scalar + (size_t)e * 8;
            float4 p = *(const float4*)esp;
            float4 q = *(const float4*)(esp + 4);
            float4 av = *(const float4*)(edge_attr + (size_t)e * 4);
            int dn = dst_in[e];
            int sn = src_in[e];
            int pos = atomicAdd(&off[dn], 1);
            poss[wvq][lane] = pos;
            eaxs[wvq][lane] = av.x;
            uint4 rv;
            rv.x = __float_as_uint(av.y);
            rv.y = __float_as_uint(av.z);
            rv.z = __float_as_uint(av.w);
            rv.w = (uint32)sn;
            rec[pos] = rv;
            a0[0] = (_Float16)p.x; a0[1] = (_Float16)p.y;
            a0[2] = (_Float16)p.z; a0[3] = (_Float16)p.w;
            a0[4] = (_Float16)q.x; a0[5] = (_Float16)q.y;
            a0[6] = (_Float16)q.z; a0[7] = (_Float16)q.w;
        }

        // h1 GEMM
        f32x4 acc1[4];
#pragma unroll
        for (int nt = 0; nt < 4; ++nt)
            acc1[nt] = __builtin_amdgcn_mfma_f32_16x16x32_f16(a0, wb1[nt], z4, 0, 0, 0);
#pragma unroll
        for (int nt = 0; nt < 4; ++nt)
#pragma unroll
            for (int i = 0; i < 4; ++i) {
                float gv = gelu_fast(acc1[nt][i] * SC_MLP1);
                int rr = (lane >> 4) * 4 + i;
                int ix = rr * 64 + 16 * nt + r15;
                shw[ix ^ ((rr & 7) << 3)] = h16(gv);
            }
        halfx8 a1[2];
#pragma unroll
        for (int ks = 0; ks < 2; ++ks) {
            int ix = r15 * 64 + 32 * ks + kq;
            a1[ks] = __builtin_bit_cast(halfx8,
                       *(const uint32x4*)&shw[ix ^ ((r15 & 7) << 3)]);
        }

        // h2 GEMM
        f32x4 acc2[4];
#pragma unroll
        for (int nt = 0; nt < 4; ++nt) {
            acc2[nt] = __builtin_amdgcn_mfma_f32_16x16x32_f16(a1[0], wb2[nt][0], z4, 0, 0, 0);
            acc2[nt] = __builtin_amdgcn_mfma_f32_16x16x32_f16(a1[1], wb2[nt][1], acc2[nt], 0, 0, 0);
        }
#pragma unroll
        for (int nt = 0; nt < 4; ++nt)
#pragma unroll
            for (int i = 0; i < 4; ++i) {
                float gv = gelu_fast(acc2[nt][i] * SC_MLP2);
                int rr = (lane >> 4) * 4 + i;
                int ix = rr * 64 + 16 * nt + r15;
                shw[ix ^ ((rr & 7) << 3)] = h16(gv);
            }
        halfx8 a2[2];
#pragma unroll
        for (int ks = 0; ks < 2; ++ks) {
            int ix = r15 * 64 + 32 * ks + kq;
            a2[ks] = __builtin_bit_cast(halfx8,
                       *(const uint32x4*)&shw[ix ^ ((r15 & 7) << 3)]);
        }

        // projection GEMM
        f32x4 accp[8];
#pragma unroll
        for (int nt = 0; nt < 8; ++nt) {
            accp[nt] = __builtin_amdgcn_mfma_f32_16x16x32_f16(a2[0], wbp[nt][0], z4, 0, 0, 0);
            accp[nt] = __builtin_amdgcn_mfma_f32_16x16x32_f16(a2[1], wbp[nt][1], accp[nt], 0, 0, 0);
        }

        // fold ea.x, write rows to scattered CSR positions (256B aligned rows)
#pragma unroll
        for (int i = 0; i < 4; ++i) {
            int rr = (lane >> 4) * 4 + i;
            float eax = eaxs[wvq][rr];
            int pos = poss[wvq][rr];
            uint32* wrow = wbuf + (size_t)pos * 64 + r15;
            wrow[0]  = pack_bf2(accp[0][i] * eax, accp[2][i]);
            wrow[16] = pack_bf2(accp[1][i] * eax, accp[3][i]);
            wrow[32] = pack_bf2(accp[4][i] * eax, accp[6][i]);
            wrow[48] = pack_bf2(accp[5][i] * eax, accp[7][i]);
        }
    }
}

// ================= K4: gather (all-linear streams + featp table) =============
__global__ __launch_bounds__(256) void gather(const int* __restrict__ off,
                                              const int* __restrict__ cnt,
                                              const uint4* __restrict__ rec,
                                              const uint32* __restrict__ wbuf,
                                              const float* __restrict__ featp,
                                              const float* __restrict__ W2_0e,
                                              const float* __restrict__ W2_1o,
                                              float* __restrict__ out) {
    int wv = threadIdx.x >> 6;
    int lane = threadIdx.x & 63;
    int node = blockIdx.x * 4 + wv;
    int u = lane & 31;
    int half = lane >> 5;

    int end = __builtin_amdgcn_readfirstlane(off[node]);   // off mutated = end
    int beg = end - __builtin_amdgcn_readfirstlane(cnt[node]);

    float a0acc = 0.f, a1x = 0.f, a1y = 0.f, a1z = 0.f;
    int offA = u + half * 32, offB = 64 + u, offC = 96 + u;

    for (int i0 = beg; i0 < end; i0 += 64) {
        int nn = end - i0;
        if (nn > 64) nn = 64;
        int idx = i0 + ((lane < nn) ? lane : 0);
        uint4 rv = rec[idx];                       // coalesced batch of 64 records
        int eyv = (int)rv.x, ezv = (int)rv.y, ewv = (int)rv.z, svv = (int)rv.w;
        for (int j0 = 0; j0 < nn; j0 += 4) {
            uint32 wl_[4];
            float fa_[4], fb_[4], fc_[4], ey_[4], ez_[4], ew_[4];
#pragma unroll
            for (int t = 0; t < 4; ++t) {
                int j = j0 + t;
                int jc = (j < nn) ? j : nn - 1;
                ey_[t] = __uint_as_float((uint32)__builtin_amdgcn_readlane(eyv, jc));
                ez_[t] = __uint_as_float((uint32)__builtin_amdgcn_readlane(ezv, jc));
                ew_[t] = __uint_as_float((uint32)__builtin_amdgcn_readlane(ewv, jc));
                int s  = __builtin_amdgcn_readlane(svv, jc);
                uint32 wl = wbuf[(size_t)(i0 + jc) * 64 + lane];   // linear stream
                wl_[t] = (j < nn) ? wl : 0u;
                const float* fp = featp + (size_t)s * 128;
                fa_[t] = fp[offA];
                fb_[t] = fp[offB];
                fc_[t] = fp[offC];
            }
#pragma unroll
            for (int t = 0; t < 4; ++t) {
                float wa = __uint_as_float(wl_[t] << 16);
                float wb = __uint_as_float(wl_[t] & 0xffff0000u);
                float va = half ? ey_[t] : 1.0f;
                float vb = half ? ez_[t] : 0.0f;
                float vc = half ? ew_[t] : 0.0f;
                float dot = fa_[t] * va + fb_[t] * vb + fc_[t] * vc;
                float w0s = half ? wb : wa;
                a0acc += w0s * dot;
                float m  = half ? wa : wb * fa_[t];
                float vx = half ? fa_[t] : ey_[t];
                float vy = half ? fb_[t] : ez_[t];
                float vz = half ? fc_[t] : ew_[t];
                a1x += m * vx; a1y += m * vy; a1z += m * vz;
            }
        }
    }

    __shared__ float red[4][256];
    float* r = red[wv];
    int c = (half << 5) + u;
    r[c] = a0acc;
    int b = 64 + c * 3;
    r[b] = a1x; r[b + 1] = a1y; r[b + 2] = a1z;
    __syncthreads();

    if (half == 0) {
        float acc = 0.f;
#pragma unroll 8
        for (int w = 0; w < 64; ++w) acc += r[w] * W2_0e[w * 32 + u];
        int o = node * 128 + u;
        out[o] = out[o] + SIN_CONV * acc;          // prefilled with COS_MIX*self
    } else {
        float c0 = 0.f, c1 = 0.f, c2 = 0.f;
#pragma unroll 8
        for (int w = 0; w < 64; ++w) {
            float bw = W2_1o[w * 32 + u];
            c0 += r[64 + w * 3 + 0] * bw;
            c1 += r[64 + w * 3 + 1] * bw;
            c2 += r[64 + w * 3 + 2] * bw;
        }
        int o = node * 128 + 32 + u * 3;
        out[o + 0] = out[o + 0] + SIN_CONV * c0;
        out[o + 1] = out[o + 1] + SIN_CONV * c1;
        out[o + 2] = out[o + 2] + SIN_CONV * c2;
    }
}

extern "C" void kernel_launch(void* const* d_in, const int* in_sizes, int n_in,
                              void* d_out, int out_size, void* d_ws, size_t ws_size,
                              hipStream_t stream) {
    const float* node_input  = (const float*)d_in[0];
    const float* edge_attr   = (const float*)d_in[1];
    const float* edge_scalar = (const float*)d_in[2];
    const float* W1_0e       = (const float*)d_in[3];
    const float* W1_1o       = (const float*)d_in[4];
    const float* W_mlp1      = (const float*)d_in[5];
    const float* W_mlp2      = (const float*)d_in[6];
    const float* Wp00        = (const float*)d_in[7];
    const float* Wp01        = (const float*)d_in[8];
    const float* Wp10        = (const float*)d_in[9];
    const float* Wp11        = (const float*)d_in[10];
    const float* W2_0e       = (const float*)d_in[11];
    const float* W2_1o       = (const float*)d_in[12];
    const int*   edge_src    = (const int*)d_in[13];
    const int*   edge_dst    = (const int*)d_in[14];
    float* ws   = (float*)d_ws;
    int*   wsI  = (int*)d_ws;
    uint32* wsU = (uint32*)d_ws;
    uint4* recp = (uint4*)(wsU + U_REC);
    float* outp = (float*)d_out;

    hipMemsetAsync(wsI + I_CNT, 0, (N_NODES + 1) * sizeof(int), stream);

    k1_fused<<<K1_NODE_BLOCKS + K1_CNT_BLOCKS + K1_PREP_BLOCKS, 256, 0, stream>>>(
        node_input, W1_0e, W1_1o, edge_dst, wsI + I_CNT,
        W_mlp1, W_mlp2, Wp00, Wp01, Wp10, Wp11, wsU + U_WF, ws + WS_FEATP, outp);
    csr_scan<<<1, 1024, 0, stream>>>(wsI + I_CNT, wsI + I_OFF);
    mlp_scatter<<<MLP_BLOCKS, 256, 0, stream>>>(edge_scalar, edge_attr,
                                                edge_src, edge_dst, wsI + I_OFF,
                                                wsU + U_WF, wsU + U_WBUF, recp);
    gather<<<N_NODES / 4, 256, 0, stream>>>(wsI + I_OFF, wsI + I_CNT, recp,
                                            wsU + U_WBUF, ws + WS_FEATP,
                                            W2_0e, W2_1o, outp);
}